// Round 15
// baseline (1270.197 us; speedup 1.0000x reference)
//
#include <hip/hip_runtime.h>

#define T_SEQ 769
#define N_SENT 768
#define E_IN 256
#define HID 128
#define G4 512
#define F_DIM 128

typedef _Float16 f16x8 __attribute__((ext_vector_type(8)));
typedef float f32x4 __attribute__((ext_vector_type(4)));

#if __has_builtin(__builtin_amdgcn_rcpf)
#define RCPF(x) __builtin_amdgcn_rcpf(x)
#else
#define RCPF(x) (1.0f / (x))
#endif

#if __has_builtin(__builtin_amdgcn_exp2f)
#define EXP2F(x) __builtin_amdgcn_exp2f(x)
#else
#define EXP2F(x) __builtin_exp2f(x)
#endif

// LDS-only barrier: waits lgkmcnt(0) then s_barrier; global prefetch loads
// stay in flight (vmcnt not drained).
#define LDS_BARRIER() asm volatile("s_waitcnt lgkmcnt(0)\n\ts_barrier" ::: "memory")

#define L2E 1.4426950408889634f

__device__ __forceinline__ float sigm_fast(float x) {
    return RCPF(1.0f + EXP2F(-L2E * x));
}
__device__ __forceinline__ float tanh_fast(float x) {
    return fmaf(2.0f, RCPF(1.0f + EXP2F(-2.0f * L2E * x)), -1.0f);
}
__device__ __forceinline__ float tanh_f(float x) {
    return 1.0f - 2.0f / (1.0f + __expf(2.0f * x));
}

// x = concat(sentence (768x256), root (1x256))
__global__ void build_x(const float* __restrict__ sent, const float* __restrict__ root,
                        float* __restrict__ x) {
    int row = blockIdx.x;
    int c = threadIdx.x;
    x[row * E_IN + c] = (row < N_SENT) ? sent[row * E_IN + c] : root[c];
}

// C[m,n] = sum_k A[ar(m),k] * B[n,k] + b0[n] + b1[n]
__global__ __launch_bounds__(256) void gemm_nt(
    const float* __restrict__ A, int lda, int M, int revA,
    const float* __restrict__ B, int ldb,
    const float* __restrict__ b0, const float* __restrict__ b1,
    float* __restrict__ C, int ldc, int K)
{
    __shared__ __align__(16) float As[16][68];
    __shared__ __align__(16) float Bs[16][68];
    int tid = threadIdx.x;
    int tx = tid & 15, ty = tid >> 4;
    int m0 = blockIdx.x * 64, n0 = blockIdx.y * 64;
    float acc[4][4] = {};
    int lrow = tid >> 2;
    int lk = (tid & 3) << 2;

    for (int k0 = 0; k0 < K; k0 += 16) {
        int m = m0 + lrow;
        float4 av = make_float4(0.f, 0.f, 0.f, 0.f);
        if (m < M) {
            int ar = revA ? (M - 1 - m) : m;
            av = *(const float4*)(A + (size_t)ar * lda + k0 + lk);
        }
        As[lk + 0][lrow] = av.x; As[lk + 1][lrow] = av.y;
        As[lk + 2][lrow] = av.z; As[lk + 3][lrow] = av.w;
        float4 bv = *(const float4*)(B + (size_t)(n0 + lrow) * ldb + k0 + lk);
        Bs[lk + 0][lrow] = bv.x; Bs[lk + 1][lrow] = bv.y;
        Bs[lk + 2][lrow] = bv.z; Bs[lk + 3][lrow] = bv.w;
        __syncthreads();
        #pragma unroll
        for (int k = 0; k < 16; ++k) {
            float4 a4 = *(const float4*)&As[k][ty * 4];
            float4 b4 = *(const float4*)&Bs[k][tx * 4];
            float aa[4] = {a4.x, a4.y, a4.z, a4.w};
            float bb[4] = {b4.x, b4.y, b4.z, b4.w};
            #pragma unroll
            for (int i = 0; i < 4; ++i)
                #pragma unroll
                for (int j = 0; j < 4; ++j)
                    acc[i][j] = fmaf(aa[i], bb[j], acc[i][j]);
        }
        __syncthreads();
    }
    float bias[4];
    #pragma unroll
    for (int j = 0; j < 4; ++j) {
        int n = n0 + tx * 4 + j;
        bias[j] = (b0 ? b0[n] : 0.f) + (b1 ? b1[n] : 0.f);
    }
    #pragma unroll
    for (int i = 0; i < 4; ++i) {
        int m = m0 + ty * 4 + i;
        if (m < M) {
            #pragma unroll
            for (int j = 0; j < 4; ++j)
                C[(size_t)m * ldc + n0 + tx * 4 + j] = acc[i][j] + bias[j];
        }
    }
}

// One BiLSTM layer, MFMA, 4-wave edition. grid = 2 (dir), block = 256.
// Wave w owns ALL FOUR gates of units 32w..32w+31 (8 N-tiles = 32 MFMA of
// 16x16x32 f16 per step, 8 independent depth-4 chains on its own matrix
// pipe at 1 wave/SIMD). Halving the wave count vs R13 halves everything the
// per-step barrier synchronizes: LDS-pipe traffic (16 reads+2 writes vs 32+8),
// barrier coordination cost, and per-SIMD MFMA issue stays 160cy.
// h broadcast into all A rows (A[m][k]=h[k]) -> acc[g][b][0] holds gate g of
// unit 32w+16b+(lane&15) in EVERY lane: no cross-lane regroup.
// B-frags (f16) preloaded once: 4 gates x 2 tiles x 4 kt x 4 VGPR = 128 VGPR.
// waves_per_eu(1,1): 1 wave/SIMD -> 512-VGPR budget, no AGPR parking.
__global__ __launch_bounds__(256)
__attribute__((amdgpu_waves_per_eu(1, 1)))
void lstm_layer(
    const float* __restrict__ pre,
    const float* __restrict__ Whh,
    float* __restrict__ L)
{
    const int d = blockIdx.x;
    const int t = threadIdx.x;
    const int wv = t >> 6;
    const int l = t & 63;
    const int n = l & 15;       // N col within tile
    const int quad = l >> 4;    // k-group for A/B fragment layout
    const int u0 = wv * 32 + n; // unit, tile b=0
    const int u1 = u0 + 16;     // unit, tile b=1

    __shared__ __align__(16) unsigned short hb[2][HID];  // h as f16, dbuf

    // B fragments: Bf[g][b][kt]; lane layout: col = lane&15, k = quad*8 + j
    f16x8 Bf[4][2][4];
    #pragma unroll
    for (int g = 0; g < 4; ++g) {
        #pragma unroll
        for (int b = 0; b < 2; ++b) {
            const float* wr = Whh + ((size_t)d * G4 + g * HID + (b ? u1 : u0)) * HID;
            #pragma unroll
            for (int kt = 0; kt < 4; ++kt) {
                const float* w8 = wr + kt * 32 + quad * 8;
                float4 v0 = *(const float4*)(w8);
                float4 v1 = *(const float4*)(w8 + 4);
                f16x8 f;
                f[0] = (_Float16)v0.x; f[1] = (_Float16)v0.y;
                f[2] = (_Float16)v0.z; f[3] = (_Float16)v0.w;
                f[4] = (_Float16)v1.x; f[5] = (_Float16)v1.y;
                f[6] = (_Float16)v1.z; f[7] = (_Float16)v1.w;
                Bf[g][b][kt] = f;
            }
        }
    }

    if (t < HID) { hb[0][t] = 0; hb[1][t] = 0; }

    // p loads: wave-uniform rolling pointer + loop-invariant lane offsets.
    const float* pp = pre + (size_t)d * T_SEQ * G4;
    float p0[4][2], p1v[4][2];
    #pragma unroll
    for (int g = 0; g < 4; ++g) {
        p0[g][0] = pp[g * HID + u0];
        p0[g][1] = pp[g * HID + u1];
    }
    pp += G4;
    #pragma unroll
    for (int g = 0; g < 4; ++g) {
        p1v[g][0] = pp[g * HID + u0];
        p1v[g][1] = pp[g * HID + u1];
    }
    pp += G4;
    float c0 = 0.f, c1 = 0.f;
    __syncthreads();

    #pragma unroll 2
    for (int s = 0; s < T_SEQ; ++s) {
        // A fragments first (earliest lgkm drain after the barrier)
        const unsigned short* hrow = &hb[s & 1][0];
        f16x8 Af[4];
        #pragma unroll
        for (int kt = 0; kt < 4; ++kt) {
            uint4 hv = *(const uint4*)(hrow + kt * 32 + quad * 8);  // 16B, broadcast
            Af[kt] = __builtin_bit_cast(f16x8, hv);
        }

        // prefetch distance 2 via rolling uniform pointer
        float p2[4][2];
        if (s + 2 < T_SEQ) {
            #pragma unroll
            for (int g = 0; g < 4; ++g) {
                p2[g][0] = pp[g * HID + u0];
                p2[g][1] = pp[g * HID + u1];
            }
        } else {
            #pragma unroll
            for (int g = 0; g < 4; ++g) { p2[g][0] = 0.f; p2[g][1] = 0.f; }
        }
        pp += G4;

        // 32 MFMA: 8 independent depth-4 chains (g,b), kt innermost-rotated
        f32x4 acc[4][2];
        #pragma unroll
        for (int g = 0; g < 4; ++g) {
            #pragma unroll
            for (int b = 0; b < 2; ++b) {
                f32x4 a = {p0[g][b], 0.f, 0.f, 0.f};
                acc[g][b] = a;
            }
        }
        #pragma unroll
        for (int kt = 0; kt < 4; ++kt) {
            #pragma unroll
            for (int g = 0; g < 4; ++g) {
                #pragma unroll
                for (int b = 0; b < 2; ++b) {
                    acc[g][b] = __builtin_amdgcn_mfma_f32_16x16x32_f16(
                        Af[kt], Bf[g][b][kt], acc[g][b], 0, 0, 0);
                }
            }
        }

        float gi0 = sigm_fast(acc[0][0][0]);
        float gf0 = sigm_fast(acc[1][0][0]);
        float gg0 = tanh_fast(acc[2][0][0]);
        float go0 = sigm_fast(acc[3][0][0]);
        float gi1 = sigm_fast(acc[0][1][0]);
        float gf1 = sigm_fast(acc[1][1][0]);
        float gg1 = tanh_fast(acc[2][1][0]);
        float go1 = sigm_fast(acc[3][1][0]);
        c0 = fmaf(gf0, c0, gi0 * gg0);
        c1 = fmaf(gf1, c1, gi1 * gg1);
        float h0 = go0 * tanh_fast(c0);
        float h1 = go1 * tanh_fast(c1);
        if (l < 16) {
            int trow = d ? (N_SENT - s) : s;
            float* Lr = L + (size_t)trow * 256 + d * HID;
            Lr[u0] = h0;
            Lr[u1] = h1;
            _Float16 hf0 = (_Float16)h0;
            _Float16 hf1 = (_Float16)h1;
            hb[(s + 1) & 1][u0] = __builtin_bit_cast(unsigned short, hf0);
            hb[(s + 1) & 1][u1] = __builtin_bit_cast(unsigned short, hf1);
        }
        #pragma unroll
        for (int g = 0; g < 4; ++g) {
            p0[g][0] = p1v[g][0]; p0[g][1] = p1v[g][1];
            p1v[g][0] = p2[g][0]; p1v[g][1] = p2[g][1];
        }
        LDS_BARRIER();
    }
}

// scores[i][j] = (i==j) ? -1e30 : b2 + sum_k w2[k]*tanh(Ap[i][k] + Bm[j][k])
__global__ __launch_bounds__(256) void scores_k(
    const float* __restrict__ Ap,   // [769][128]
    const float* __restrict__ Bm,   // [768][128]
    const float* __restrict__ w2,
    const float* __restrict__ b2,
    float* __restrict__ out)        // [769][768]
{
    __shared__ __align__(16) float Asl[32][132];
    __shared__ __align__(16) float Bsl[32][132];
    __shared__ __align__(16) float w2s[F_DIM];
    int tid = threadIdx.x;
    int i0 = blockIdx.x * 32, j0 = blockIdx.y * 32;

    for (int e = tid; e < 1024; e += 256) {
        int r = e >> 5;
        int qq = (e & 31) << 2;
        float4 av = (i0 + r < T_SEQ)
                        ? *(const float4*)(Ap + (size_t)(i0 + r) * F_DIM + qq)
                        : make_float4(0.f, 0.f, 0.f, 0.f);
        *(float4*)&Asl[r][qq] = av;
        float4 bv = *(const float4*)(Bm + (size_t)(j0 + r) * F_DIM + qq);
        *(float4*)&Bsl[r][qq] = bv;
    }
    if (tid < 32) {
        *(float4*)&w2s[tid * 4] = *(const float4*)(w2 + tid * 4);
    }
    __syncthreads();

    int tx = tid & 15, ty = tid >> 4;
    float s[2][2] = {};
    #pragma unroll 8
    for (int k4 = 0; k4 < F_DIM; k4 += 4) {
        float4 a0 = *(const float4*)&Asl[ty * 2][k4];
        float4 a1 = *(const float4*)&Asl[ty * 2 + 1][k4];
        float4 b0 = *(const float4*)&Bsl[tx * 2][k4];
        float4 b1v = *(const float4*)&Bsl[tx * 2 + 1][k4];
        float4 wv = *(const float4*)&w2s[k4];
        float aa[2][4] = {{a0.x, a0.y, a0.z, a0.w}, {a1.x, a1.y, a1.z, a1.w}};
        float bb[2][4] = {{b0.x, b0.y, b0.z, b0.w}, {b1v.x, b1v.y, b1v.z, b1v.w}};
        float ww[4] = {wv.x, wv.y, wv.z, wv.w};
        #pragma unroll
        for (int kk = 0; kk < 4; ++kk)
            #pragma unroll
            for (int ii = 0; ii < 2; ++ii)
                #pragma unroll
                for (int jj = 0; jj < 2; ++jj)
                    s[ii][jj] = fmaf(ww[kk], tanh_f(aa[ii][kk] + bb[jj][kk]), s[ii][jj]);
    }

    float bb2 = b2[0];
    #pragma unroll
    for (int ii = 0; ii < 2; ++ii) {
        int i = i0 + ty * 2 + ii;
        if (i < T_SEQ) {
            #pragma unroll
            for (int jj = 0; jj < 2; ++jj) {
                int j = j0 + tx * 2 + jj;
                out[(size_t)i * N_SENT + j] =
                    (i == j) ? -1.0e30f : (s[ii][jj] + bb2);
            }
        }
    }
}

extern "C" void kernel_launch(void* const* d_in, const int* in_sizes, int n_in,
                              void* d_out, int out_size, void* d_ws, size_t ws_size,
                              hipStream_t stream) {
    const float* sent = (const float*)d_in[0];
    const float* root = (const float*)d_in[2];
    const float* Wih  = (const float*)d_in[3];  // (2,2,512,256)
    const float* Whh  = (const float*)d_in[4];  // (2,2,512,128)
    const float* bih  = (const float*)d_in[5];  // (2,2,512)
    const float* bhh  = (const float*)d_in[6];  // (2,2,512)
    const float* W1   = (const float*)d_in[7];  // (128,512)
    const float* b1   = (const float*)d_in[8];  // (128)
    const float* w2   = (const float*)d_in[9];  // (128)
    const float* b2   = (const float*)d_in[10]; // (1)
    float* out = (float*)d_out;
    float* ws = (float*)d_ws;

    float* x   = ws;                       // 769*256
    float* pre = x + T_SEQ * E_IN;         // 2*769*512
    float* L0  = pre + 2 * T_SEQ * G4;     // 769*256
    float* L1  = L0 + T_SEQ * 256;         // 769*256
    float* Ap  = L1 + T_SEQ * 256;         // 769*128
    float* Bm  = Ap + T_SEQ * F_DIM;       // 768*128

    build_x<<<T_SEQ, E_IN, 0, stream>>>(sent, root, x);

    dim3 b256(256);
    dim3 gpre(13, 8);
    gemm_nt<<<gpre, b256, 0, stream>>>(x, E_IN, T_SEQ, 0,
                                       Wih, E_IN, bih, bhh, pre, G4, E_IN);
    gemm_nt<<<gpre, b256, 0, stream>>>(x, E_IN, T_SEQ, 1,
                                       Wih + (size_t)G4 * E_IN, E_IN,
                                       bih + G4, bhh + G4,
                                       pre + (size_t)T_SEQ * G4, G4, E_IN);
    lstm_layer<<<2, 256, 0, stream>>>(pre, Whh, L0);

    gemm_nt<<<gpre, b256, 0, stream>>>(L0, 256, T_SEQ, 0,
                                       Wih + (size_t)2 * G4 * E_IN, 256,
                                       bih + 2 * G4, bhh + 2 * G4, pre, G4, 256);
    gemm_nt<<<gpre, b256, 0, stream>>>(L0, 256, T_SEQ, 1,
                                       Wih + (size_t)3 * G4 * E_IN, 256,
                                       bih + 3 * G4, bhh + 3 * G4,
                                       pre + (size_t)T_SEQ * G4, G4, 256);
    lstm_layer<<<2, 256, 0, stream>>>(pre, Whh + (size_t)2 * G4 * HID, L1);

    gemm_nt<<<dim3(13, 2), b256, 0, stream>>>(L1, 256, T_SEQ, 0,
                                              W1, 512, b1, nullptr, Ap, F_DIM, 256);
    gemm_nt<<<dim3(12, 2), b256, 0, stream>>>(L1, 256, N_SENT, 0,
                                              W1 + 256, 512, nullptr, nullptr, Bm, F_DIM, 256);

    scores_k<<<dim3(25, 24), b256, 0, stream>>>(Ap, Bm, w2, b2, out);
}

// Round 16
// 975.381 us; speedup vs baseline: 1.3023x; 1.3023x over previous
//
#include <hip/hip_runtime.h>

#define T_SEQ 769
#define N_SENT 768
#define E_IN 256
#define HID 128
#define G4 512
#define F_DIM 128

typedef _Float16 f16x8 __attribute__((ext_vector_type(8)));
typedef float f32x4 __attribute__((ext_vector_type(4)));

#if __has_builtin(__builtin_amdgcn_rcpf)
#define RCPF(x) __builtin_amdgcn_rcpf(x)
#else
#define RCPF(x) (1.0f / (x))
#endif

#if __has_builtin(__builtin_amdgcn_exp2f)
#define EXP2F(x) __builtin_amdgcn_exp2f(x)
#else
#define EXP2F(x) __builtin_exp2f(x)
#endif

// LDS-only barrier: waits lgkmcnt(0) then s_barrier; global prefetch loads
// stay in flight (vmcnt not drained).
#define LDS_BARRIER() asm volatile("s_waitcnt lgkmcnt(0)\n\ts_barrier" ::: "memory")

#define L2E 1.4426950408889634f

__device__ __forceinline__ float sigm_fast(float x) {
    return RCPF(1.0f + EXP2F(-L2E * x));
}
__device__ __forceinline__ float tanh_fast(float x) {
    return fmaf(2.0f, RCPF(1.0f + EXP2F(-2.0f * L2E * x)), -1.0f);
}
__device__ __forceinline__ float tanh_f(float x) {
    return 1.0f - 2.0f / (1.0f + __expf(2.0f * x));
}

// ---------------- pre-GEMM, layer 0 (x built inline from sent/root) --------
// pre[d][m][n] = sum_k x[ar(m)][k] * Wih0[d][n][k] + bih0[d][n] + bhh0[d][n]
// grid (13, 8, 2), block 256. d = blockIdx.z; bwd (d=1) reads x reversed.
__global__ __launch_bounds__(256) void pre_gemm_l0(
    const float* __restrict__ sent, const float* __restrict__ root,
    const float* __restrict__ Wih, const float* __restrict__ bih,
    const float* __restrict__ bhh, float* __restrict__ pre)
{
    const int d = blockIdx.z;
    const float* B = Wih + (size_t)d * G4 * E_IN;
    const float* b0 = bih + (size_t)d * G4;
    const float* b1 = bhh + (size_t)d * G4;
    float* C = pre + (size_t)d * T_SEQ * G4;

    __shared__ __align__(16) float As[16][68];
    __shared__ __align__(16) float Bs[16][68];
    int tid = threadIdx.x;
    int tx = tid & 15, ty = tid >> 4;
    int m0 = blockIdx.x * 64, n0 = blockIdx.y * 64;
    float acc[4][4] = {};
    int lrow = tid >> 2;
    int lk = (tid & 3) << 2;

    for (int k0 = 0; k0 < E_IN; k0 += 16) {
        int m = m0 + lrow;
        float4 av = make_float4(0.f, 0.f, 0.f, 0.f);
        if (m < T_SEQ) {
            int ar = d ? (N_SENT - m) : m;  // reversed for bwd
            av = (ar < N_SENT)
                     ? *(const float4*)(sent + (size_t)ar * E_IN + k0 + lk)
                     : *(const float4*)(root + k0 + lk);
        }
        As[lk + 0][lrow] = av.x; As[lk + 1][lrow] = av.y;
        As[lk + 2][lrow] = av.z; As[lk + 3][lrow] = av.w;
        float4 bv = *(const float4*)(B + (size_t)(n0 + lrow) * E_IN + k0 + lk);
        Bs[lk + 0][lrow] = bv.x; Bs[lk + 1][lrow] = bv.y;
        Bs[lk + 2][lrow] = bv.z; Bs[lk + 3][lrow] = bv.w;
        __syncthreads();
        #pragma unroll
        for (int k = 0; k < 16; ++k) {
            float4 a4 = *(const float4*)&As[k][ty * 4];
            float4 b4 = *(const float4*)&Bs[k][tx * 4];
            float aa[4] = {a4.x, a4.y, a4.z, a4.w};
            float bb[4] = {b4.x, b4.y, b4.z, b4.w};
            #pragma unroll
            for (int i = 0; i < 4; ++i)
                #pragma unroll
                for (int j = 0; j < 4; ++j)
                    acc[i][j] = fmaf(aa[i], bb[j], acc[i][j]);
        }
        __syncthreads();
    }
    float bias[4];
    #pragma unroll
    for (int j = 0; j < 4; ++j) {
        int n = n0 + tx * 4 + j;
        bias[j] = b0[n] + b1[n];
    }
    #pragma unroll
    for (int i = 0; i < 4; ++i) {
        int m = m0 + ty * 4 + i;
        if (m < T_SEQ) {
            #pragma unroll
            for (int j = 0; j < 4; ++j)
                C[(size_t)m * G4 + n0 + tx * 4 + j] = acc[i][j] + bias[j];
        }
    }
}

// ---------------- pre-GEMM, layer 1 (A = L0, both directions) --------------
// grid (13, 8, 2), block 256. d = blockIdx.z; Wih base is layer-1.
__global__ __launch_bounds__(256) void pre_gemm_l1(
    const float* __restrict__ L0,
    const float* __restrict__ Wih, const float* __restrict__ bih,
    const float* __restrict__ bhh, float* __restrict__ pre)
{
    const int d = blockIdx.z;
    const float* B = Wih + (size_t)(2 + d) * G4 * E_IN;
    const float* b0 = bih + (size_t)(2 + d) * G4;
    const float* b1 = bhh + (size_t)(2 + d) * G4;
    float* C = pre + (size_t)d * T_SEQ * G4;

    __shared__ __align__(16) float As[16][68];
    __shared__ __align__(16) float Bs[16][68];
    int tid = threadIdx.x;
    int tx = tid & 15, ty = tid >> 4;
    int m0 = blockIdx.x * 64, n0 = blockIdx.y * 64;
    float acc[4][4] = {};
    int lrow = tid >> 2;
    int lk = (tid & 3) << 2;

    for (int k0 = 0; k0 < 256; k0 += 16) {
        int m = m0 + lrow;
        float4 av = make_float4(0.f, 0.f, 0.f, 0.f);
        if (m < T_SEQ) {
            int ar = d ? (N_SENT - m) : m;
            av = *(const float4*)(L0 + (size_t)ar * 256 + k0 + lk);
        }
        As[lk + 0][lrow] = av.x; As[lk + 1][lrow] = av.y;
        As[lk + 2][lrow] = av.z; As[lk + 3][lrow] = av.w;
        float4 bv = *(const float4*)(B + (size_t)(n0 + lrow) * 256 + k0 + lk);
        Bs[lk + 0][lrow] = bv.x; Bs[lk + 1][lrow] = bv.y;
        Bs[lk + 2][lrow] = bv.z; Bs[lk + 3][lrow] = bv.w;
        __syncthreads();
        #pragma unroll
        for (int k = 0; k < 16; ++k) {
            float4 a4 = *(const float4*)&As[k][ty * 4];
            float4 b4 = *(const float4*)&Bs[k][tx * 4];
            float aa[4] = {a4.x, a4.y, a4.z, a4.w};
            float bb[4] = {b4.x, b4.y, b4.z, b4.w};
            #pragma unroll
            for (int i = 0; i < 4; ++i)
                #pragma unroll
                for (int j = 0; j < 4; ++j)
                    acc[i][j] = fmaf(aa[i], bb[j], acc[i][j]);
        }
        __syncthreads();
    }
    float bias[4];
    #pragma unroll
    for (int j = 0; j < 4; ++j) {
        int n = n0 + tx * 4 + j;
        bias[j] = b0[n] + b1[n];
    }
    #pragma unroll
    for (int i = 0; i < 4; ++i) {
        int m = m0 + ty * 4 + i;
        if (m < T_SEQ) {
            #pragma unroll
            for (int j = 0; j < 4; ++j)
                C[(size_t)m * G4 + n0 + tx * 4 + j] = acc[i][j] + bias[j];
        }
    }
}

// ---------------- Ap/Bm GEMM (merged via blockIdx.z) -----------------------
// z=0: Ap[m][n] = L1[m]·W1[n][0:256] + b1[n]   (M=769)
// z=1: Bm[m][n] = L1[m]·W1[n][256:512]         (M=768)
// grid (13, 2, 2), block 256. N=128.
__global__ __launch_bounds__(256) void ab_gemm(
    const float* __restrict__ L1, const float* __restrict__ W1,
    const float* __restrict__ b1, float* __restrict__ Ap,
    float* __restrict__ Bm)
{
    const int z = blockIdx.z;
    const int M = z ? N_SENT : T_SEQ;
    const float* B = W1 + (z ? 256 : 0);
    float* C = z ? Bm : Ap;

    __shared__ __align__(16) float As[16][68];
    __shared__ __align__(16) float Bs[16][68];
    int tid = threadIdx.x;
    int tx = tid & 15, ty = tid >> 4;
    int m0 = blockIdx.x * 64, n0 = blockIdx.y * 64;
    float acc[4][4] = {};
    int lrow = tid >> 2;
    int lk = (tid & 3) << 2;

    for (int k0 = 0; k0 < 256; k0 += 16) {
        int m = m0 + lrow;
        float4 av = make_float4(0.f, 0.f, 0.f, 0.f);
        if (m < M) av = *(const float4*)(L1 + (size_t)m * 256 + k0 + lk);
        As[lk + 0][lrow] = av.x; As[lk + 1][lrow] = av.y;
        As[lk + 2][lrow] = av.z; As[lk + 3][lrow] = av.w;
        float4 bv = *(const float4*)(B + (size_t)(n0 + lrow) * 512 + k0 + lk);
        Bs[lk + 0][lrow] = bv.x; Bs[lk + 1][lrow] = bv.y;
        Bs[lk + 2][lrow] = bv.z; Bs[lk + 3][lrow] = bv.w;
        __syncthreads();
        #pragma unroll
        for (int k = 0; k < 16; ++k) {
            float4 a4 = *(const float4*)&As[k][ty * 4];
            float4 b4 = *(const float4*)&Bs[k][tx * 4];
            float aa[4] = {a4.x, a4.y, a4.z, a4.w};
            float bb[4] = {b4.x, b4.y, b4.z, b4.w};
            #pragma unroll
            for (int i = 0; i < 4; ++i)
                #pragma unroll
                for (int j = 0; j < 4; ++j)
                    acc[i][j] = fmaf(aa[i], bb[j], acc[i][j]);
        }
        __syncthreads();
    }
    float bias[4];
    #pragma unroll
    for (int j = 0; j < 4; ++j) {
        int n = n0 + tx * 4 + j;
        bias[j] = z ? 0.f : b1[n];
    }
    #pragma unroll
    for (int i = 0; i < 4; ++i) {
        int m = m0 + ty * 4 + i;
        if (m < M) {
            #pragma unroll
            for (int j = 0; j < 4; ++j)
                C[(size_t)m * F_DIM + n0 + tx * 4 + j] = acc[i][j] + bias[j];
        }
    }
}

// ---------------- LSTM layer (R13 config: MFMA, 8 waves, 2/SIMD) -----------
// Wave w: gates i,f,g,o of units 16w..16w+15 via 16 mfma_f32_16x16x32_f16.
// h broadcast into all A rows so acc_g[0] = y+p in EVERY lane. p loads via
// wave-uniform rolling pointer; depth-2 MFMA chains; unroll 2; one LDS-only
// barrier per step (prefetch rides across). 2 waves/SIMD hides chain latency
// (R15 proved 1/SIMD exposes it: 531 vs 400 us).
__global__ __launch_bounds__(512)
__attribute__((amdgpu_waves_per_eu(2, 2)))
void lstm_layer(
    const float* __restrict__ pre,
    const float* __restrict__ Whh,
    float* __restrict__ L)
{
    const int d = blockIdx.x;
    const int t = threadIdx.x;
    const int wv = t >> 6;
    const int l = t & 63;
    const int n = l & 15;
    const int quad = l >> 4;
    const int u = wv * 16 + n;

    __shared__ __align__(16) unsigned short hb[2][HID];  // h as f16, dbuf

    f16x8 Bf[4][4];
    #pragma unroll
    for (int g = 0; g < 4; ++g) {
        const float* wr = Whh + ((size_t)d * G4 + g * HID + u) * HID;
        #pragma unroll
        for (int kt = 0; kt < 4; ++kt) {
            const float* w8 = wr + kt * 32 + quad * 8;
            float4 v0 = *(const float4*)(w8);
            float4 v1 = *(const float4*)(w8 + 4);
            f16x8 f;
            f[0] = (_Float16)v0.x; f[1] = (_Float16)v0.y;
            f[2] = (_Float16)v0.z; f[3] = (_Float16)v0.w;
            f[4] = (_Float16)v1.x; f[5] = (_Float16)v1.y;
            f[6] = (_Float16)v1.z; f[7] = (_Float16)v1.w;
            Bf[g][kt] = f;
        }
    }

    if (t < HID) { hb[0][t] = 0; hb[1][t] = 0; }

    const float* pp = pre + (size_t)d * T_SEQ * G4;
    const int po = u;
    float p0[4], p1v[4];
    #pragma unroll
    for (int g = 0; g < 4; ++g) p0[g] = pp[g * HID + po];
    pp += G4;
    #pragma unroll
    for (int g = 0; g < 4; ++g) p1v[g] = pp[g * HID + po];
    pp += G4;
    float c = 0.f;
    __syncthreads();

    #pragma unroll 2
    for (int s = 0; s < T_SEQ; ++s) {
        const unsigned short* hrow = &hb[s & 1][0];
        f16x8 Af[4];
        #pragma unroll
        for (int kt = 0; kt < 4; ++kt) {
            uint4 hv = *(const uint4*)(hrow + kt * 32 + quad * 8);
            Af[kt] = __builtin_bit_cast(f16x8, hv);
        }

        float p2[4];
        if (s + 2 < T_SEQ) {
            #pragma unroll
            for (int g = 0; g < 4; ++g) p2[g] = pp[g * HID + po];
        } else {
            p2[0] = p2[1] = p2[2] = p2[3] = 0.f;
        }
        pp += G4;

        f32x4 aA0 = {p0[0], 0.f, 0.f, 0.f}, aB0 = {0.f, 0.f, 0.f, 0.f};
        f32x4 aA1 = {p0[1], 0.f, 0.f, 0.f}, aB1 = {0.f, 0.f, 0.f, 0.f};
        f32x4 aA2 = {p0[2], 0.f, 0.f, 0.f}, aB2 = {0.f, 0.f, 0.f, 0.f};
        f32x4 aA3 = {p0[3], 0.f, 0.f, 0.f}, aB3 = {0.f, 0.f, 0.f, 0.f};
        aA0 = __builtin_amdgcn_mfma_f32_16x16x32_f16(Af[0], Bf[0][0], aA0, 0, 0, 0);
        aA1 = __builtin_amdgcn_mfma_f32_16x16x32_f16(Af[0], Bf[1][0], aA1, 0, 0, 0);
        aA2 = __builtin_amdgcn_mfma_f32_16x16x32_f16(Af[0], Bf[2][0], aA2, 0, 0, 0);
        aA3 = __builtin_amdgcn_mfma_f32_16x16x32_f16(Af[0], Bf[3][0], aA3, 0, 0, 0);
        aB0 = __builtin_amdgcn_mfma_f32_16x16x32_f16(Af[2], Bf[0][2], aB0, 0, 0, 0);
        aB1 = __builtin_amdgcn_mfma_f32_16x16x32_f16(Af[2], Bf[1][2], aB1, 0, 0, 0);
        aB2 = __builtin_amdgcn_mfma_f32_16x16x32_f16(Af[2], Bf[2][2], aB2, 0, 0, 0);
        aB3 = __builtin_amdgcn_mfma_f32_16x16x32_f16(Af[2], Bf[3][2], aB3, 0, 0, 0);
        aA0 = __builtin_amdgcn_mfma_f32_16x16x32_f16(Af[1], Bf[0][1], aA0, 0, 0, 0);
        aA1 = __builtin_amdgcn_mfma_f32_16x16x32_f16(Af[1], Bf[1][1], aA1, 0, 0, 0);
        aA2 = __builtin_amdgcn_mfma_f32_16x16x32_f16(Af[1], Bf[2][1], aA2, 0, 0, 0);
        aA3 = __builtin_amdgcn_mfma_f32_16x16x32_f16(Af[1], Bf[3][1], aA3, 0, 0, 0);
        aB0 = __builtin_amdgcn_mfma_f32_16x16x32_f16(Af[3], Bf[0][3], aB0, 0, 0, 0);
        aB1 = __builtin_amdgcn_mfma_f32_16x16x32_f16(Af[3], Bf[1][3], aB1, 0, 0, 0);
        aB2 = __builtin_amdgcn_mfma_f32_16x16x32_f16(Af[3], Bf[2][3], aB2, 0, 0, 0);
        aB3 = __builtin_amdgcn_mfma_f32_16x16x32_f16(Af[3], Bf[3][3], aB3, 0, 0, 0);

        float gi = sigm_fast(aA0[0] + aB0[0]);
        float gf = sigm_fast(aA1[0] + aB1[0]);
        float gg = tanh_fast(aA2[0] + aB2[0]);
        float go = sigm_fast(aA3[0] + aB3[0]);
        c = fmaf(gf, c, gi * gg);
        float h = go * tanh_fast(c);
        if (l < 16) {
            int trow = d ? (N_SENT - s) : s;
            L[(size_t)trow * 256 + d * HID + u] = h;
            _Float16 hf = (_Float16)h;
            hb[(s + 1) & 1][u] = __builtin_bit_cast(unsigned short, hf);
        }
        #pragma unroll
        for (int g = 0; g < 4; ++g) { p0[g] = p1v[g]; p1v[g] = p2[g]; }
        LDS_BARRIER();
    }
}

// scores[i][j] = (i==j) ? -1e30 : b2 + sum_k w2[k]*tanh(Ap[i][k] + Bm[j][k])
__global__ __launch_bounds__(256) void scores_k(
    const float* __restrict__ Ap,   // [769][128]
    const float* __restrict__ Bm,   // [768][128]
    const float* __restrict__ w2,
    const float* __restrict__ b2,
    float* __restrict__ out)        // [769][768]
{
    __shared__ __align__(16) float Asl[32][132];
    __shared__ __align__(16) float Bsl[32][132];
    __shared__ __align__(16) float w2s[F_DIM];
    int tid = threadIdx.x;
    int i0 = blockIdx.x * 32, j0 = blockIdx.y * 32;

    for (int e = tid; e < 1024; e += 256) {
        int r = e >> 5;
        int qq = (e & 31) << 2;
        float4 av = (i0 + r < T_SEQ)
                        ? *(const float4*)(Ap + (size_t)(i0 + r) * F_DIM + qq)
                        : make_float4(0.f, 0.f, 0.f, 0.f);
        *(float4*)&Asl[r][qq] = av;
        float4 bv = *(const float4*)(Bm + (size_t)(j0 + r) * F_DIM + qq);
        *(float4*)&Bsl[r][qq] = bv;
    }
    if (tid < 32) {
        *(float4*)&w2s[tid * 4] = *(const float4*)(w2 + tid * 4);
    }
    __syncthreads();

    int tx = tid & 15, ty = tid >> 4;
    float s[2][2] = {};
    #pragma unroll 8
    for (int k4 = 0; k4 < F_DIM; k4 += 4) {
        float4 a0 = *(const float4*)&Asl[ty * 2][k4];
        float4 a1 = *(const float4*)&Asl[ty * 2 + 1][k4];
        float4 b0 = *(const float4*)&Bsl[tx * 2][k4];
        float4 b1v = *(const float4*)&Bsl[tx * 2 + 1][k4];
        float4 wv = *(const float4*)&w2s[k4];
        float aa[2][4] = {{a0.x, a0.y, a0.z, a0.w}, {a1.x, a1.y, a1.z, a1.w}};
        float bb[2][4] = {{b0.x, b0.y, b0.z, b0.w}, {b1v.x, b1v.y, b1v.z, b1v.w}};
        float ww[4] = {wv.x, wv.y, wv.z, wv.w};
        #pragma unroll
        for (int kk = 0; kk < 4; ++kk)
            #pragma unroll
            for (int ii = 0; ii < 2; ++ii)
                #pragma unroll
                for (int jj = 0; jj < 2; ++jj)
                    s[ii][jj] = fmaf(ww[kk], tanh_f(aa[ii][kk] + bb[jj][kk]), s[ii][jj]);
    }

    float bb2 = b2[0];
    #pragma unroll
    for (int ii = 0; ii < 2; ++ii) {
        int i = i0 + ty * 2 + ii;
        if (i < T_SEQ) {
            #pragma unroll
            for (int jj = 0; jj < 2; ++jj) {
                int j = j0 + tx * 2 + jj;
                out[(size_t)i * N_SENT + j] =
                    (i == j) ? -1.0e30f : (s[ii][jj] + bb2);
            }
        }
    }
}

extern "C" void kernel_launch(void* const* d_in, const int* in_sizes, int n_in,
                              void* d_out, int out_size, void* d_ws, size_t ws_size,
                              hipStream_t stream) {
    const float* sent = (const float*)d_in[0];
    const float* root = (const float*)d_in[2];
    const float* Wih  = (const float*)d_in[3];  // (2,2,512,256)
    const float* Whh  = (const float*)d_in[4];  // (2,2,512,128)
    const float* bih  = (const float*)d_in[5];  // (2,2,512)
    const float* bhh  = (const float*)d_in[6];  // (2,2,512)
    const float* W1   = (const float*)d_in[7];  // (128,512)
    const float* b1   = (const float*)d_in[8];  // (128)
    const float* w2   = (const float*)d_in[9];  // (128)
    const float* b2   = (const float*)d_in[10]; // (1)
    float* out = (float*)d_out;
    float* ws = (float*)d_ws;

    float* pre = ws;                        // 2*769*512
    float* L0  = pre + 2 * T_SEQ * G4;      // 769*256
    float* L1  = L0 + T_SEQ * 256;          // 769*256
    float* Ap  = L1 + T_SEQ * 256;          // 769*128
    float* Bm  = Ap + T_SEQ * F_DIM;        // 768*128

    dim3 b256(256);

    pre_gemm_l0<<<dim3(13, 8, 2), b256, 0, stream>>>(sent, root, Wih, bih, bhh, pre);
    lstm_layer<<<2, 512, 0, stream>>>(pre, Whh, L0);

    pre_gemm_l1<<<dim3(13, 8, 2), b256, 0, stream>>>(L0, Wih, bih, bhh, pre);
    lstm_layer<<<2, 512, 0, stream>>>(pre, Whh + (size_t)2 * G4 * HID, L1);

    ab_gemm<<<dim3(13, 2, 2), b256, 0, stream>>>(L1, W1, b1, Ap, Bm);

    scores_k<<<dim3(25, 24), b256, 0, stream>>>(Ap, Bm, w2, b2, out);
}

// Round 17
// 867.598 us; speedup vs baseline: 1.4640x; 1.1242x over previous
//
#include <hip/hip_runtime.h>
#include <hip/hip_fp8.h>

#define T_SEQ 769
#define N_SENT 768
#define E_IN 256
#define HID 128
#define G4 512
#define F_DIM 128

typedef float f32x4 __attribute__((ext_vector_type(4)));
typedef int i32x8 __attribute__((ext_vector_type(8)));

#if __has_builtin(__builtin_amdgcn_rcpf)
#define RCPF(x) __builtin_amdgcn_rcpf(x)
#else
#define RCPF(x) (1.0f / (x))
#endif

#if __has_builtin(__builtin_amdgcn_exp2f)
#define EXP2F(x) __builtin_amdgcn_exp2f(x)
#else
#define EXP2F(x) __builtin_exp2f(x)
#endif

// LDS-only barrier: waits lgkmcnt(0) then s_barrier; global prefetch loads
// stay in flight (vmcnt not drained).
#define LDS_BARRIER() asm volatile("s_waitcnt lgkmcnt(0)\n\ts_barrier" ::: "memory")

#define L2E 1.4426950408889634f

__device__ __forceinline__ float sigm_fast(float x) {
    return RCPF(1.0f + EXP2F(-L2E * x));
}
__device__ __forceinline__ float tanh_fast(float x) {
    return fmaf(2.0f, RCPF(1.0f + EXP2F(-2.0f * L2E * x)), -1.0f);
}
__device__ __forceinline__ float tanh_f(float x) {
    return 1.0f - 2.0f / (1.0f + __expf(2.0f * x));
}

__device__ __forceinline__ unsigned char f32_to_e4m3(float x) {
    __hip_fp8_e4m3 q(x);
    return (unsigned char)q.__x;
}

// ---------------- pre-GEMM, layer 0 (x built inline from sent/root) --------
__global__ __launch_bounds__(256) void pre_gemm_l0(
    const float* __restrict__ sent, const float* __restrict__ root,
    const float* __restrict__ Wih, const float* __restrict__ bih,
    const float* __restrict__ bhh, float* __restrict__ pre)
{
    const int d = blockIdx.z;
    const float* B = Wih + (size_t)d * G4 * E_IN;
    const float* b0 = bih + (size_t)d * G4;
    const float* b1 = bhh + (size_t)d * G4;
    float* C = pre + (size_t)d * T_SEQ * G4;

    __shared__ __align__(16) float As[16][68];
    __shared__ __align__(16) float Bs[16][68];
    int tid = threadIdx.x;
    int tx = tid & 15, ty = tid >> 4;
    int m0 = blockIdx.x * 64, n0 = blockIdx.y * 64;
    float acc[4][4] = {};
    int lrow = tid >> 2;
    int lk = (tid & 3) << 2;

    for (int k0 = 0; k0 < E_IN; k0 += 16) {
        int m = m0 + lrow;
        float4 av = make_float4(0.f, 0.f, 0.f, 0.f);
        if (m < T_SEQ) {
            int ar = d ? (N_SENT - m) : m;
            av = (ar < N_SENT)
                     ? *(const float4*)(sent + (size_t)ar * E_IN + k0 + lk)
                     : *(const float4*)(root + k0 + lk);
        }
        As[lk + 0][lrow] = av.x; As[lk + 1][lrow] = av.y;
        As[lk + 2][lrow] = av.z; As[lk + 3][lrow] = av.w;
        float4 bv = *(const float4*)(B + (size_t)(n0 + lrow) * E_IN + k0 + lk);
        Bs[lk + 0][lrow] = bv.x; Bs[lk + 1][lrow] = bv.y;
        Bs[lk + 2][lrow] = bv.z; Bs[lk + 3][lrow] = bv.w;
        __syncthreads();
        #pragma unroll
        for (int k = 0; k < 16; ++k) {
            float4 a4 = *(const float4*)&As[k][ty * 4];
            float4 b4 = *(const float4*)&Bs[k][tx * 4];
            float aa[4] = {a4.x, a4.y, a4.z, a4.w};
            float bb[4] = {b4.x, b4.y, b4.z, b4.w};
            #pragma unroll
            for (int i = 0; i < 4; ++i)
                #pragma unroll
                for (int j = 0; j < 4; ++j)
                    acc[i][j] = fmaf(aa[i], bb[j], acc[i][j]);
        }
        __syncthreads();
    }
    float bias[4];
    #pragma unroll
    for (int j = 0; j < 4; ++j) {
        int n = n0 + tx * 4 + j;
        bias[j] = b0[n] + b1[n];
    }
    #pragma unroll
    for (int i = 0; i < 4; ++i) {
        int m = m0 + ty * 4 + i;
        if (m < T_SEQ) {
            #pragma unroll
            for (int j = 0; j < 4; ++j)
                C[(size_t)m * G4 + n0 + tx * 4 + j] = acc[i][j] + bias[j];
        }
    }
}

// ---------------- pre-GEMM, layer 1 ---------------------------------------
__global__ __launch_bounds__(256) void pre_gemm_l1(
    const float* __restrict__ L0,
    const float* __restrict__ Wih, const float* __restrict__ bih,
    const float* __restrict__ bhh, float* __restrict__ pre)
{
    const int d = blockIdx.z;
    const float* B = Wih + (size_t)(2 + d) * G4 * E_IN;
    const float* b0 = bih + (size_t)(2 + d) * G4;
    const float* b1 = bhh + (size_t)(2 + d) * G4;
    float* C = pre + (size_t)d * T_SEQ * G4;

    __shared__ __align__(16) float As[16][68];
    __shared__ __align__(16) float Bs[16][68];
    int tid = threadIdx.x;
    int tx = tid & 15, ty = tid >> 4;
    int m0 = blockIdx.x * 64, n0 = blockIdx.y * 64;
    float acc[4][4] = {};
    int lrow = tid >> 2;
    int lk = (tid & 3) << 2;

    for (int k0 = 0; k0 < 256; k0 += 16) {
        int m = m0 + lrow;
        float4 av = make_float4(0.f, 0.f, 0.f, 0.f);
        if (m < T_SEQ) {
            int ar = d ? (N_SENT - m) : m;
            av = *(const float4*)(L0 + (size_t)ar * 256 + k0 + lk);
        }
        As[lk + 0][lrow] = av.x; As[lk + 1][lrow] = av.y;
        As[lk + 2][lrow] = av.z; As[lk + 3][lrow] = av.w;
        float4 bv = *(const float4*)(B + (size_t)(n0 + lrow) * 256 + k0 + lk);
        Bs[lk + 0][lrow] = bv.x; Bs[lk + 1][lrow] = bv.y;
        Bs[lk + 2][lrow] = bv.z; Bs[lk + 3][lrow] = bv.w;
        __syncthreads();
        #pragma unroll
        for (int k = 0; k < 16; ++k) {
            float4 a4 = *(const float4*)&As[k][ty * 4];
            float4 b4 = *(const float4*)&Bs[k][tx * 4];
            float aa[4] = {a4.x, a4.y, a4.z, a4.w};
            float bb[4] = {b4.x, b4.y, b4.z, b4.w};
            #pragma unroll
            for (int i = 0; i < 4; ++i)
                #pragma unroll
                for (int j = 0; j < 4; ++j)
                    acc[i][j] = fmaf(aa[i], bb[j], acc[i][j]);
        }
        __syncthreads();
    }
    float bias[4];
    #pragma unroll
    for (int j = 0; j < 4; ++j) {
        int n = n0 + tx * 4 + j;
        bias[j] = b0[n] + b1[n];
    }
    #pragma unroll
    for (int i = 0; i < 4; ++i) {
        int m = m0 + ty * 4 + i;
        if (m < T_SEQ) {
            #pragma unroll
            for (int j = 0; j < 4; ++j)
                C[(size_t)m * G4 + n0 + tx * 4 + j] = acc[i][j] + bias[j];
        }
    }
}

// ---------------- Ap/Bm GEMM (merged via blockIdx.z) -----------------------
__global__ __launch_bounds__(256) void ab_gemm(
    const float* __restrict__ L1, const float* __restrict__ W1,
    const float* __restrict__ b1, float* __restrict__ Ap,
    float* __restrict__ Bm)
{
    const int z = blockIdx.z;
    const int M = z ? N_SENT : T_SEQ;
    const float* B = W1 + (z ? 256 : 0);
    float* C = z ? Bm : Ap;

    __shared__ __align__(16) float As[16][68];
    __shared__ __align__(16) float Bs[16][68];
    int tid = threadIdx.x;
    int tx = tid & 15, ty = tid >> 4;
    int m0 = blockIdx.x * 64, n0 = blockIdx.y * 64;
    float acc[4][4] = {};
    int lrow = tid >> 2;
    int lk = (tid & 3) << 2;

    for (int k0 = 0; k0 < 256; k0 += 16) {
        int m = m0 + lrow;
        float4 av = make_float4(0.f, 0.f, 0.f, 0.f);
        if (m < M) av = *(const float4*)(L1 + (size_t)m * 256 + k0 + lk);
        As[lk + 0][lrow] = av.x; As[lk + 1][lrow] = av.y;
        As[lk + 2][lrow] = av.z; As[lk + 3][lrow] = av.w;
        float4 bv = *(const float4*)(B + (size_t)(n0 + lrow) * 512 + k0 + lk);
        Bs[lk + 0][lrow] = bv.x; Bs[lk + 1][lrow] = bv.y;
        Bs[lk + 2][lrow] = bv.z; Bs[lk + 3][lrow] = bv.w;
        __syncthreads();
        #pragma unroll
        for (int k = 0; k < 16; ++k) {
            float4 a4 = *(const float4*)&As[k][ty * 4];
            float4 b4 = *(const float4*)&Bs[k][tx * 4];
            float aa[4] = {a4.x, a4.y, a4.z, a4.w};
            float bb[4] = {b4.x, b4.y, b4.z, b4.w};
            #pragma unroll
            for (int i = 0; i < 4; ++i)
                #pragma unroll
                for (int j = 0; j < 4; ++j)
                    acc[i][j] = fmaf(aa[i], bb[j], acc[i][j]);
        }
        __syncthreads();
    }
    float bias[4];
    #pragma unroll
    for (int j = 0; j < 4; ++j) {
        int n = n0 + tx * 4 + j;
        bias[j] = z ? 0.f : b1[n];
    }
    #pragma unroll
    for (int i = 0; i < 4; ++i) {
        int m = m0 + ty * 4 + i;
        if (m < M) {
            #pragma unroll
            for (int j = 0; j < 4; ++j)
                C[(size_t)m * F_DIM + n0 + tx * 4 + j] = acc[i][j] + bias[j];
        }
    }
}

// ---------------- LSTM layer: K=128 block-scaled fp8 MFMA ------------------
// grid = 2 (dir), block = 512 (8 waves, 2/SIMD). Wave w: gates i,f,g,o of
// units 16w..16w+15 via FOUR mfma_scale_f32_16x16x128_f8f6f4 (scales=1.0,
// fmt=e4m3). K=128 in ONE instruction at ~2x the f16 FLOP rate cuts the
// per-step matrix-pipe occupancy from ~620cy (R13: 128 mfma/CU of 16x16x32
// f16) to ~275cy (32 mfma/CU). h is stored in LDS as fp8 (128B): A-frag is
// 2 ds_read_b128 per wave (lane: row=l&15, k=(l>>4)*32+j). h broadcast into
// all A rows -> acc[g][0] = gate g of unit 16w+(l&15) in every lane.
// B-frags (Whh as e4m3) preloaded: 4 x 8 VGPR = 32 VGPRs.
__global__ __launch_bounds__(512)
__attribute__((amdgpu_waves_per_eu(2, 2)))
void lstm_layer(
    const float* __restrict__ pre,
    const float* __restrict__ Whh,
    float* __restrict__ L)
{
    const int d = blockIdx.x;
    const int t = threadIdx.x;
    const int wv = t >> 6;
    const int l = t & 63;
    const int n = l & 15;
    const int quad = l >> 4;
    const int u = wv * 16 + n;

    __shared__ __align__(16) unsigned char hb[2][HID];  // h as fp8 e4m3, dbuf

    // B fragments: lane holds Whh[g*128+u][quad*32 + j], j=0..31, as e4m3
    i32x8 Bf[4];
    #pragma unroll
    for (int g = 0; g < 4; ++g) {
        const float* wr = Whh + ((size_t)d * G4 + g * HID + u) * HID + quad * 32;
        i32x8 bv;
        #pragma unroll
        for (int w8 = 0; w8 < 8; ++w8) {
            unsigned x = 0;
            #pragma unroll
            for (int b = 0; b < 4; ++b) {
                x |= (unsigned)f32_to_e4m3(wr[w8 * 4 + b]) << (8 * b);
            }
            bv[w8] = (int)x;
        }
        Bf[g] = bv;
    }

    if (t < HID) { hb[0][t] = 0; hb[1][t] = 0; }

    // p loads: wave-uniform rolling pointer + loop-invariant lane offset
    const float* pp = pre + (size_t)d * T_SEQ * G4;
    const int po = u;
    float p0[4], p1v[4];
    #pragma unroll
    for (int g = 0; g < 4; ++g) p0[g] = pp[g * HID + po];
    pp += G4;
    #pragma unroll
    for (int g = 0; g < 4; ++g) p1v[g] = pp[g * HID + po];
    pp += G4;
    float c = 0.f;
    __syncthreads();

    #pragma unroll 2
    for (int s = 0; s < T_SEQ; ++s) {
        // A fragment: h fp8 bytes [quad*32 .. quad*32+31] (2 b128 reads,
        // 4 distinct 16B addresses per wave -> conflict-free broadcast)
        const uint4* hp = (const uint4*)&hb[s & 1][quad * 32];
        uint4 lo = hp[0];
        uint4 hi = hp[1];
        i32x8 Af = {(int)lo.x, (int)lo.y, (int)lo.z, (int)lo.w,
                    (int)hi.x, (int)hi.y, (int)hi.z, (int)hi.w};

        float p2[4];
        if (s + 2 < T_SEQ) {
            #pragma unroll
            for (int g = 0; g < 4; ++g) p2[g] = pp[g * HID + po];
        } else {
            p2[0] = p2[1] = p2[2] = p2[3] = 0.f;
        }
        pp += G4;

        // 4 independent K=128 fp8 MFMAs (fmt 0 = e4m3; scales = 1.0: E8M0
        // byte 0x7F = 2^0 for all four 32-blocks)
        f32x4 a0 = {p0[0], 0.f, 0.f, 0.f};
        f32x4 a1 = {p0[1], 0.f, 0.f, 0.f};
        f32x4 a2 = {p0[2], 0.f, 0.f, 0.f};
        f32x4 a3 = {p0[3], 0.f, 0.f, 0.f};
        a0 = __builtin_amdgcn_mfma_scale_f32_16x16x128_f8f6f4(
            Af, Bf[0], a0, 0, 0, 0, 0x7F7F7F7F, 0, 0x7F7F7F7F);
        a1 = __builtin_amdgcn_mfma_scale_f32_16x16x128_f8f6f4(
            Af, Bf[1], a1, 0, 0, 0, 0x7F7F7F7F, 0, 0x7F7F7F7F);
        a2 = __builtin_amdgcn_mfma_scale_f32_16x16x128_f8f6f4(
            Af, Bf[2], a2, 0, 0, 0, 0x7F7F7F7F, 0, 0x7F7F7F7F);
        a3 = __builtin_amdgcn_mfma_scale_f32_16x16x128_f8f6f4(
            Af, Bf[3], a3, 0, 0, 0, 0x7F7F7F7F, 0, 0x7F7F7F7F);

        float gi = sigm_fast(a0[0]);
        float gf = sigm_fast(a1[0]);
        float gg = tanh_fast(a2[0]);
        float go = sigm_fast(a3[0]);
        c = fmaf(gf, c, gi * gg);
        float h = go * tanh_fast(c);
        if (l < 16) {
            int trow = d ? (N_SENT - s) : s;
            L[(size_t)trow * 256 + d * HID + u] = h;
            hb[(s + 1) & 1][u] = f32_to_e4m3(h);
        }
        #pragma unroll
        for (int g = 0; g < 4; ++g) { p0[g] = p1v[g]; p1v[g] = p2[g]; }
        LDS_BARRIER();
    }
}

// scores[i][j] = (i==j) ? -1e30 : b2 + sum_k w2[k]*tanh(Ap[i][k] + Bm[j][k])
__global__ __launch_bounds__(256) void scores_k(
    const float* __restrict__ Ap,   // [769][128]
    const float* __restrict__ Bm,   // [768][128]
    const float* __restrict__ w2,
    const float* __restrict__ b2,
    float* __restrict__ out)        // [769][768]
{
    __shared__ __align__(16) float Asl[32][132];
    __shared__ __align__(16) float Bsl[32][132];
    __shared__ __align__(16) float w2s[F_DIM];
    int tid = threadIdx.x;
    int i0 = blockIdx.x * 32, j0 = blockIdx.y * 32;

    for (int e = tid; e < 1024; e += 256) {
        int r = e >> 5;
        int qq = (e & 31) << 2;
        float4 av = (i0 + r < T_SEQ)
                        ? *(const float4*)(Ap + (size_t)(i0 + r) * F_DIM + qq)
                        : make_float4(0.f, 0.f, 0.f, 0.f);
        *(float4*)&Asl[r][qq] = av;
        float4 bv = *(const float4*)(Bm + (size_t)(j0 + r) * F_DIM + qq);
        *(float4*)&Bsl[r][qq] = bv;
    }
    if (tid < 32) {
        *(float4*)&w2s[tid * 4] = *(const float4*)(w2 + tid * 4);
    }
    __syncthreads();

    int tx = tid & 15, ty = tid >> 4;
    float s[2][2] = {};
    #pragma unroll 8
    for (int k4 = 0; k4 < F_DIM; k4 += 4) {
        float4 a0 = *(const float4*)&Asl[ty * 2][k4];
        float4 a1 = *(const float4*)&Asl[ty * 2 + 1][k4];
        float4 b0 = *(const float4*)&Bsl[tx * 2][k4];
        float4 b1v = *(const float4*)&Bsl[tx * 2 + 1][k4];
        float4 wv = *(const float4*)&w2s[k4];
        float aa[2][4] = {{a0.x, a0.y, a0.z, a0.w}, {a1.x, a1.y, a1.z, a1.w}};
        float bb[2][4] = {{b0.x, b0.y, b0.z, b0.w}, {b1v.x, b1v.y, b1v.z, b1v.w}};
        float ww[4] = {wv.x, wv.y, wv.z, wv.w};
        #pragma unroll
        for (int kk = 0; kk < 4; ++kk)
            #pragma unroll
            for (int ii = 0; ii < 2; ++ii)
                #pragma unroll
                for (int jj = 0; jj < 2; ++jj)
                    s[ii][jj] = fmaf(ww[kk], tanh_f(aa[ii][kk] + bb[jj][kk]), s[ii][jj]);
    }

    float bb2 = b2[0];
    #pragma unroll
    for (int ii = 0; ii < 2; ++ii) {
        int i = i0 + ty * 2 + ii;
        if (i < T_SEQ) {
            #pragma unroll
            for (int jj = 0; jj < 2; ++jj) {
                int j = j0 + tx * 2 + jj;
                out[(size_t)i * N_SENT + j] =
                    (i == j) ? -1.0e30f : (s[ii][jj] + bb2);
            }
        }
    }
}

extern "C" void kernel_launch(void* const* d_in, const int* in_sizes, int n_in,
                              void* d_out, int out_size, void* d_ws, size_t ws_size,
                              hipStream_t stream) {
    const float* sent = (const float*)d_in[0];
    const float* root = (const float*)d_in[2];
    const float* Wih  = (const float*)d_in[3];  // (2,2,512,256)
    const float* Whh  = (const float*)d_in[4];  // (2,2,512,128)
    const float* bih  = (const float*)d_in[5];  // (2,2,512)
    const float* bhh  = (const float*)d_in[6];  // (2,2,512)
    const float* W1   = (const float*)d_in[7];  // (128,512)
    const float* b1   = (const float*)d_in[8];  // (128)
    const float* w2   = (const float*)d_in[9];  // (128)
    const float* b2   = (const float*)d_in[10]; // (1)
    float* out = (float*)d_out;
    float* ws = (float*)d_ws;

    float* pre = ws;                        // 2*769*512
    float* L0  = pre + 2 * T_SEQ * G4;      // 769*256
    float* L1  = L0 + T_SEQ * 256;          // 769*256
    float* Ap  = L1 + T_SEQ * 256;          // 769*128
    float* Bm  = Ap + T_SEQ * F_DIM;        // 768*128

    dim3 b256(256);

    pre_gemm_l0<<<dim3(13, 8, 2), b256, 0, stream>>>(sent, root, Wih, bih, bhh, pre);
    lstm_layer<<<2, 512, 0, stream>>>(pre, Whh, L0);

    pre_gemm_l1<<<dim3(13, 8, 2), b256, 0, stream>>>(L0, Wih, bih, bhh, pre);
    lstm_layer<<<2, 512, 0, stream>>>(pre, Whh + (size_t)2 * G4 * HID, L1);

    ab_gemm<<<dim3(13, 2, 2), b256, 0, stream>>>(L1, W1, b1, Ap, Bm);

    scores_k<<<dim3(25, 24), b256, 0, stream>>>(Ap, Bm, w2, b2, out);
}